// Round 6
// baseline (289.974 us; speedup 1.0000x reference)
//
#include <hip/hip_runtime.h>
#include <math.h>

typedef __bf16 bf16;
typedef __bf16 bf16x8 __attribute__((ext_vector_type(8)));
typedef float f32x4 __attribute__((ext_vector_type(4)));
typedef unsigned short u16;
typedef unsigned int u32;

constexpr int BATCH = 32;
constexpr int CH    = 512;   // C
constexpr int CI    = 256;   // C/2
constexpr int NSP   = 1024;  // H*W
constexpr int OCH   = 768;   // 3*CI (theta|phi|g concat)
constexpr float EPSV = 1e-5f;
constexpr float LOG2E = 1.4426950408889634f;

#if __has_builtin(__builtin_amdgcn_exp2f)
#define EXP2F(x) __builtin_amdgcn_exp2f(x)
#else
#define EXP2F(x) exp2f(x)
#endif

// async global->LDS, 16B per lane: LDS dest = wave-uniform base + lane*16
__device__ __forceinline__ void gload_lds16(const bf16* g, bf16* l) {
    __builtin_amdgcn_global_load_lds(
        (const __attribute__((address_space(1))) void*)g,
        (__attribute__((address_space(3))) void*)l, 16, 0, 0);
}

__device__ __forceinline__ u32 pack_bf16(float a, float b) {
    union { bf16 h; u16 u; } ca, cb;
    ca.h = (bf16)a; cb.h = (bf16)b;
    return (u32)ca.u | ((u32)cb.u << 16);
}

// ---------------------------------------------------------------------------
// K0a: weights -> bf16, k-blocked tiles of 64. Also zeroes the BN sums.
// ---------------------------------------------------------------------------
__global__ void prep_weights(const float* __restrict__ Wg, const float* __restrict__ Wt,
                             const float* __restrict__ Wp, const float* __restrict__ Wz,
                             bf16* __restrict__ wc, bf16* __restrict__ wz,
                             float* __restrict__ sums) {
    int tid = blockIdx.x * 256 + threadIdx.x;
    if (tid < 1024) sums[tid] = 0.0f;
    if (tid < OCH * CH) {
        int r = tid / CH, c = tid % CH;
        float v;
        if (r < 256)      v = Wt[r * CH + c];
        else if (r < 512) v = Wp[(r - 256) * CH + c];
        else              v = Wg[(r - 512) * CH + c];
        wc[(size_t)(c >> 6) * (OCH * 64) + r * 64 + (c & 63)] = (bf16)v;
    } else {
        int t2 = tid - OCH * CH;
        if (t2 < CH * CI) {
            int r = t2 / CI, o = t2 % CI;
            wz[(size_t)(o >> 6) * (CH * 64) + r * 64 + (o & 63)] = (bf16)Wz[r * CI + o];
        }
    }
}

// ---------------------------------------------------------------------------
// K0b: x [b][c][n] fp32 -> xb [b][kt][n][64] bf16 (64x64 LDS transpose tiles)
// ---------------------------------------------------------------------------
__global__ void transpose_x(const float* __restrict__ x, bf16* __restrict__ xb) {
    __shared__ bf16 tile[64][64];
    int b = blockIdx.z, kt = blockIdx.y, nb = blockIdx.x;
    int t = threadIdx.x;
    {
        int c_loc = t >> 2;
        int nq = t & 3;
        const float* src = x + ((size_t)b * CH + kt * 64 + c_loc) * NSP + nb * 64 + nq * 16;
        float vv[16];
        *(float4*)(vv + 0)  = *(const float4*)(src + 0);
        *(float4*)(vv + 4)  = *(const float4*)(src + 4);
        *(float4*)(vv + 8)  = *(const float4*)(src + 8);
        *(float4*)(vv + 12) = *(const float4*)(src + 12);
        int nbase = nq * 16;
        #pragma unroll
        for (int i = 0; i < 16; ++i) tile[nbase + i][c_loc] = (bf16)vv[i];
    }
    __syncthreads();
    {
        int n_loc = t >> 2;
        int cq = t & 3;
        bf16* dst = xb + ((((size_t)b * 8 + kt) * NSP) + nb * 64 + n_loc) * 64 + cq * 16;
        *(uint4*)(dst)     = *(const uint4*)&tile[n_loc][cq * 16];
        *(uint4*)(dst + 8) = *(const uint4*)&tile[n_loc][cq * 16 + 8];
    }
}

// ---------------------------------------------------------------------------
// K1: fused projection GEMM.
//   theta -> linear [b][n][ci], PRE-SCALED by log2(e) (exp2 softmax);
//   phi/g -> BLOCKED MFMA-fragment tiles; V (g) kv-order PERMUTED (R4).
// ---------------------------------------------------------------------------
__launch_bounds__(256, 2)
__global__ void proj_gemm(const bf16* __restrict__ xb, const bf16* __restrict__ wc,
                          const float* __restrict__ bt, const float* __restrict__ bp,
                          const float* __restrict__ bg,
                          bf16* __restrict__ theta, bf16* __restrict__ phi_t,
                          bf16* __restrict__ gt_t) {
    constexpr int LDA = 72;
    __shared__ __align__(16) bf16 sm[2 * 128 * LDA];
    bf16* As = sm;
    bf16* Bs = sm + 128 * LDA;
    int b = blockIdx.z;
    int n0 = blockIdx.y * 128;
    int oc0 = blockIdx.x * 128;
    int t = threadIdx.x, lane = t & 63, wid = t >> 6;
    int wm = wid >> 1, wn = wid & 1;
    int l15 = lane & 15, quad = lane >> 4;

    f32x4 acc[4][4] = {};
    for (int kt = 0; kt < 8; ++kt) {
        __syncthreads();
        const bf16* asrc = xb + ((((size_t)b * 8 + kt) * NSP) + n0) * 64;
        const bf16* bsrc = wc + ((size_t)kt * OCH + oc0) * 64;
        for (int s = t; s < 1024; s += 256) {
            int row = s >> 3, c8 = s & 7;
            *(uint4*)&As[row * LDA + c8 * 8] = *(const uint4*)(asrc + (size_t)s * 8);
            *(uint4*)&Bs[row * LDA + c8 * 8] = *(const uint4*)(bsrc + (size_t)s * 8);
        }
        __syncthreads();
        #pragma unroll
        for (int kc = 0; kc < 2; ++kc) {
            bf16x8 af[4], bfv[4];
            #pragma unroll
            for (int i = 0; i < 4; ++i) {
                af[i]  = *(const bf16x8*)&As[(wm * 64 + i * 16 + l15) * LDA + kc * 32 + quad * 8];
                bfv[i] = *(const bf16x8*)&Bs[(wn * 64 + i * 16 + l15) * LDA + kc * 32 + quad * 8];
            }
            #pragma unroll
            for (int i = 0; i < 4; ++i)
                #pragma unroll
                for (int j = 0; j < 4; ++j)
                    acc[i][j] = __builtin_amdgcn_mfma_f32_16x16x32_bf16(af[i], bfv[j], acc[i][j], 0, 0, 0);
        }
    }
    if (oc0 < 256) {
        // theta: linear [b][n][ci], scaled by log2(e) so attn uses exp2
        #pragma unroll
        for (int j = 0; j < 4; ++j) {
            int och = oc0 + wn * 64 + j * 16 + l15;
            float bv = bt[och];
            #pragma unroll
            for (int i = 0; i < 4; ++i) {
                int nrow = n0 + wm * 64 + i * 16 + quad * 4;
                bf16* p = theta + ((size_t)b * NSP + nrow) * CI + och;
                #pragma unroll
                for (int r = 0; r < 4; ++r)
                    p[(size_t)r * CI] = (bf16)((acc[i][j][r] + bv) * LOG2E);
            }
        }
    } else if (oc0 < 512) {
        // phi: blocked K-tiles
        bf16* dstb = phi_t + (size_t)b * 262144;
        #pragma unroll
        for (int j = 0; j < 4; ++j) {
            int och = (oc0 - 256) + wn * 64 + j * 16 + l15;
            float bv = bp[och];
            int kc = och >> 5, qd = (och >> 3) & 3, e = och & 7;
            #pragma unroll
            for (int i = 0; i < 4; ++i) {
                int nrow = n0 + wm * 64 + i * 16 + quad * 4;   // row16 base = quad*4
                int kt = nrow >> 5, h = (nrow >> 4) & 1;
                bf16* p = dstb + (size_t)kt * 8192 +
                          (size_t)(((h * 8 + kc) * 64 + qd * 16 + quad * 4) * 8) + e;
                #pragma unroll
                for (int r = 0; r < 4; ++r)
                    p[r * 8] = (bf16)(acc[i][j][r] + bv);
            }
        }
    } else {
        // g: transpose tile in LDS, then write PERMUTED blocked V-tiles.
        constexpr int LT = 136;
        int obase = oc0 - 512;
        __syncthreads();
        bf16* T = sm;
        #pragma unroll
        for (int j = 0; j < 4; ++j) {
            int och = wn * 64 + j * 16 + l15;
            float bv = bg[obase + och];
            #pragma unroll
            for (int i = 0; i < 4; ++i) {
                int nl = wm * 64 + i * 16 + quad * 4;
                bf16 tmp[4];
                #pragma unroll
                for (int r = 0; r < 4; ++r) tmp[r] = (bf16)(acc[i][j][r] + bv);
                *(uint2*)&T[och * LT + nl] = *(const uint2*)tmp;
            }
        }
        __syncthreads();
        bf16* dstb = gt_t + (size_t)b * 262144;
        for (int s = t; s < 2048; s += 256) {
            int row = s >> 4, part = s & 15;
            int o = obase + row;
            int kglob = n0 + part * 8;
            int kt = kglob >> 5, qd = (kglob >> 3) & 3;
            int qa = (2 * qd) & 3, qb = (2 * qd + 1) & 3;
            int jb = (qd & 2) * 2;             // 0 or 4
            bf16* base = dstb + (size_t)kt * 8192 + (size_t)((o >> 4) * 512 + (o & 15) * 8);
            *(uint2*)(base + qa * 128 + jb) = *(const uint2*)&T[row * LT + part * 8];
            *(uint2*)(base + qb * 128 + jb) = *(const uint2*)&T[row * LT + part * 8 + 4];
        }
    }
}

// ---------------------------------------------------------------------------
// K2: fused attention. R6 = R4 skeleton (512 blocks, 2/CU, 1 barrier/iter,
// lane-local softmax + permuted-V lane-local PV) + :
//   - T15 pipeline: QK^T(kt+1) issued BEFORE softmax/PV(kt) -> MFMA pipe
//     overlaps the softmax VALU chain; S-result wait leaves the critical path.
//   - K dbuf (tile parity <-> buffer), V TRIPLE-buffered so the stage target
//     never collides with the PV-read tile. LDS 80 KB -> still 2 blocks/CU.
//   - exp2 softmax (theta pre-scaled by log2e); defer-max THR = 11.5424
//     (== 8 nats).
// ---------------------------------------------------------------------------

#define STAGE(TILE, KDST, VDST) {                                           \
    const bf16* ksrc_ = ph_b + (size_t)(TILE) * 8192;                       \
    const bf16* vsrc_ = gt_b + (size_t)(TILE) * 8192;                       \
    bf16* kd_ = (KDST) + w * 2048;                                          \
    bf16* vd_ = (VDST) + w * 2048;                                          \
    _Pragma("unroll")                                                       \
    for (int i_ = 0; i_ < 4; ++i_) {                                        \
        gload_lds16(ksrc_ + i_ * 512, kd_ + i_ * 512);                      \
        gload_lds16(vsrc_ + i_ * 512, vd_ + i_ * 512);                      \
    } }

#define QKT(S0, S1, KBUF) {                                                 \
    S0 = (f32x4){}; S1 = (f32x4){};                                         \
    __builtin_amdgcn_s_setprio(1);                                          \
    _Pragma("unroll")                                                       \
    for (int kc_ = 0; kc_ < 8; ++kc_) {                                     \
        bf16x8 kf0_ = *(const bf16x8*)((KBUF) + kc_ * 512 + lane * 8);      \
        bf16x8 kf1_ = *(const bf16x8*)((KBUF) + 4096 + kc_ * 512 + lane * 8);\
        S0 = __builtin_amdgcn_mfma_f32_16x16x32_bf16(kf0_, qf[kc_], S0, 0, 0, 0); \
        S1 = __builtin_amdgcn_mfma_f32_16x16x32_bf16(kf1_, qf[kc_], S1, 0, 0, 0); \
    }                                                                       \
    __builtin_amdgcn_s_setprio(0); }

#define SMPV(S0, S1, VBUF) {                                                \
    float c_ = fmaxf(fmaxf(fmaxf(S0[0], S0[1]), fmaxf(S0[2], S0[3])),       \
                     fmaxf(fmaxf(S1[0], S1[1]), fmaxf(S1[2], S1[3])));      \
    c_ = fmaxf(c_, __shfl_xor(c_, 16));                                     \
    c_ = fmaxf(c_, __shfl_xor(c_, 32));                                     \
    int flag_ = (c_ > m + 11.5424f) ? 1 : 0;                                \
    if (__any(flag_)) {                                                     \
        float mn_ = fmaxf(m, c_);                                           \
        float al_ = EXP2F(m - mn_);                                         \
        m = mn_; ps *= al_;                                                 \
        float a0_ = __shfl(al_, quad * 4 + 0);                              \
        float a1_ = __shfl(al_, quad * 4 + 1);                              \
        float a2_ = __shfl(al_, quad * 4 + 2);                              \
        float a3_ = __shfl(al_, quad * 4 + 3);                              \
        _Pragma("unroll")                                                   \
        for (int nt_ = 0; nt_ < 16; ++nt_) {                                \
            oacc[nt_][0] *= a0_; oacc[nt_][1] *= a1_;                       \
            oacc[nt_][2] *= a2_; oacc[nt_][3] *= a3_;                       \
        } }                                                                 \
    float p0_ = EXP2F(S0[0] - m), p1_ = EXP2F(S0[1] - m);                   \
    float p2_ = EXP2F(S0[2] - m), p3_ = EXP2F(S0[3] - m);                   \
    float p4_ = EXP2F(S1[0] - m), p5_ = EXP2F(S1[1] - m);                   \
    float p6_ = EXP2F(S1[2] - m), p7_ = EXP2F(S1[3] - m);                   \
    ps += ((p0_ + p1_) + (p2_ + p3_)) + ((p4_ + p5_) + (p6_ + p7_));        \
    bf16x8 pf_;                                                             \
    { union { u32 u[4]; bf16x8 v; } cvt_;                                   \
      cvt_.u[0] = pack_bf16(p0_, p1_); cvt_.u[1] = pack_bf16(p2_, p3_);     \
      cvt_.u[2] = pack_bf16(p4_, p5_); cvt_.u[3] = pack_bf16(p6_, p7_);     \
      pf_ = cvt_.v; }                                                       \
    __builtin_amdgcn_s_setprio(1);                                          \
    _Pragma("unroll")                                                       \
    for (int nt_ = 0; nt_ < 16; ++nt_) {                                    \
        bf16x8 vf_ = *(const bf16x8*)((VBUF) + nt_ * 512 + lane * 8);       \
        oacc[nt_] = __builtin_amdgcn_mfma_f32_16x16x32_bf16(pf_, vf_, oacc[nt_], 0, 0, 0); \
    }                                                                       \
    __builtin_amdgcn_s_setprio(0); }

__launch_bounds__(256, 2)
__global__ void attn_kernel(const bf16* __restrict__ theta, const bf16* __restrict__ phi_t,
                            const bf16* __restrict__ gt_t, bf16* __restrict__ y) {
    // layout: KB0 @0 | KB1 @16K | V0 @32K | V1 @48K | V2 @64K   (80 KB)
    __shared__ __align__(16) char smem[81920];

    int id = blockIdx.x;
    int j = id >> 3;
    int qt = j & 15;
    int b = (id & 7) + 8 * (j >> 4);

    int t = threadIdx.x, lane = t & 63, w = t >> 6;
    int l15 = lane & 15, quad = lane >> 4;

    const bf16* ph_b = phi_t + (size_t)b * 262144 + w * 2048 + lane * 8;
    const bf16* gt_b = gt_t + (size_t)b * 262144 + w * 2048 + lane * 8;

    // Q fragments directly from global (one-time); lane->q, quad->d-chunk
    bf16x8 qf[8];
    {
        const bf16* qrow = theta + ((size_t)b * NSP + qt * 64 + w * 16 + l15) * CI;
        #pragma unroll
        for (int kc = 0; kc < 8; ++kc)
            qf[kc] = *(const bf16x8*)(qrow + kc * 32 + quad * 8);
    }

    bf16* KB0 = (bf16*)smem;
    bf16* KB1 = (bf16*)(smem + 16384);
    bf16* Va  = (bf16*)(smem + 32768);
    bf16* Vb  = (bf16*)(smem + 49152);
    bf16* Vc  = (bf16*)(smem + 65536);

    // prologue: K[0]->KB0, V[0]->Va, K[1]->KB1, V[1]->Vb
    STAGE(0, KB0, Va);
    STAGE(1, KB1, Vb);
    __syncthreads();

    f32x4 oacc[16] = {};
    float m = -1e30f;
    float ps = 0.0f;
    f32x4 sA0, sA1, sB0, sB1;

    QKT(sA0, sA1, KB0);          // S(tile 0)
    __syncthreads();             // protect KB0 before iter-0 restage

    for (int kt2 = 0; kt2 < 32; kt2 += 2) {
        // ---- even body: kt = kt2 ----
        if (kt2 < 30) STAGE(kt2 + 2, KB0, Vc);
        QKT(sB0, sB1, KB1);      // S(kt2+1), overlaps softmax below
        SMPV(sA0, sA1, Va);      // softmax+PV for tile kt2
        __syncthreads();
        { bf16* tmp = Va; Va = Vb; Vb = Vc; Vc = tmp; }
        // ---- odd body: kt = kt2 + 1 ----
        if (kt2 < 30) {
            STAGE(kt2 + 3, KB1, Vc);
            QKT(sA0, sA1, KB0);  // S(kt2+2)
        }
        SMPV(sB0, sB1, Va);      // softmax+PV for tile kt2+1
        __syncthreads();
        { bf16* tmp = Va; Va = Vb; Vb = Vc; Vc = tmp; }
    }

    // final denom: combine the 4 quad-partials for each q, then redistribute
    ps += __shfl_xor(ps, 16);
    ps += __shfl_xor(ps, 32);
    float inv = 1.0f / ps;
    float inv0 = __shfl(inv, quad * 4 + 0);
    float inv1 = __shfl(inv, quad * 4 + 1);
    float inv2 = __shfl(inv, quad * 4 + 2);
    float inv3 = __shfl(inv, quad * 4 + 3);

    int nrow = qt * 64 + w * 16 + quad * 4;
    #pragma unroll
    for (int nt = 0; nt < 16; ++nt) {
        int o = nt * 16 + l15;
        bf16* dst = y + ((((size_t)b * 4 + (o >> 6)) * NSP) + nrow) * 64 + (o & 63);
        dst[0]           = (bf16)(oacc[nt][0] * inv0);
        dst[(size_t)64]  = (bf16)(oacc[nt][1] * inv1);
        dst[(size_t)128] = (bf16)(oacc[nt][2] * inv2);
        dst[(size_t)192] = (bf16)(oacc[nt][3] * inv3);
    }
}

// ---------------------------------------------------------------------------
// K3: output GEMM + fused BN stats. LDS cross-wave combine -> 128 atomic
// pairs per block. 4 blocks/CU (LDS 38.9 KB, VGPR 72).
// ---------------------------------------------------------------------------
__launch_bounds__(256, 4)
__global__ void out_gemm(const bf16* __restrict__ y, const bf16* __restrict__ wz,
                         const float* __restrict__ bz, float* __restrict__ wy,
                         float* __restrict__ sums) {
    constexpr int LDA = 72;
    __shared__ __align__(16) bf16 As[128 * LDA];
    __shared__ __align__(16) bf16 Bs[128 * LDA];
    __shared__ float redS[128][2], redS2[128][2];
    int b = blockIdx.z;
    int co0 = blockIdx.y * 128;
    int n0 = blockIdx.x * 128;
    int t = threadIdx.x, lane = t & 63, wid = t >> 6;
    int wm = wid >> 1, wn = wid & 1;
    int l15 = lane & 15, quad = lane >> 4;

    f32x4 acc[4][4] = {};
    for (int kt = 0; kt < 4; ++kt) {
        __syncthreads();
        const bf16* asrc = wz + ((size_t)kt * CH + co0) * 64;
        const bf16* bsrc = y + ((((size_t)b * 4 + kt) * NSP) + n0) * 64;
        for (int s = t; s < 1024; s += 256) {
            int row = s >> 3, c8 = s & 7;
            *(uint4*)&As[row * LDA + c8 * 8] = *(const uint4*)(asrc + (size_t)s * 8);
            *(uint4*)&Bs[row * LDA + c8 * 8] = *(const uint4*)(bsrc + (size_t)s * 8);
        }
        __syncthreads();
        #pragma unroll
        for (int kc = 0; kc < 2; ++kc) {
            bf16x8 af[4], bfv[4];
            #pragma unroll
            for (int i = 0; i < 4; ++i) {
                af[i]  = *(const bf16x8*)&As[(wm * 64 + i * 16 + l15) * LDA + kc * 32 + quad * 8];
                bfv[i] = *(const bf16x8*)&Bs[(wn * 64 + i * 16 + l15) * LDA + kc * 32 + quad * 8];
            }
            #pragma unroll
            for (int i = 0; i < 4; ++i)
                #pragma unroll
                for (int j = 0; j < 4; ++j)
                    acc[i][j] = __builtin_amdgcn_mfma_f32_16x16x32_bf16(af[i], bfv[j], acc[i][j], 0, 0, 0);
        }
    }
    #pragma unroll
    for (int i = 0; i < 4; ++i) {
        int cbase = co0 + wm * 64 + i * 16 + quad * 4;
        #pragma unroll
        for (int r = 0; r < 4; ++r) {
            int c = cbase + r;
            float bv = bz[c];
            float s = 0.f, s2 = 0.f;
            #pragma unroll
            for (int jj = 0; jj < 4; ++jj) {
                int n = n0 + wn * 64 + jj * 16 + l15;
                float v = acc[i][jj][r] + bv;
                wy[((size_t)b * CH + c) * NSP + n] = v;
                s += v; s2 += v * v;
            }
            s  += __shfl_xor(s, 1);  s2 += __shfl_xor(s2, 1);
            s  += __shfl_xor(s, 2);  s2 += __shfl_xor(s2, 2);
            s  += __shfl_xor(s, 4);  s2 += __shfl_xor(s2, 4);
            s  += __shfl_xor(s, 8);  s2 += __shfl_xor(s2, 8);
            if (l15 == 0) {
                int cl = wm * 64 + i * 16 + quad * 4 + r;
                redS[cl][wn]  = s;
                redS2[cl][wn] = s2;
            }
        }
    }
    __syncthreads();
    if (t < 128) {
        atomicAdd(&sums[co0 + t],      redS[t][0] + redS[t][1]);
        atomicAdd(&sums[CH + co0 + t], redS2[t][0] + redS2[t][1]);
    }
}

// ---------------------------------------------------------------------------
// K4: BN normalize + affine + residual, in-place on d_out. float4.
// ---------------------------------------------------------------------------
__global__ void bn_finalize(float* __restrict__ out, const float* __restrict__ x,
                            const float* __restrict__ sums,
                            const float* __restrict__ gamma, const float* __restrict__ beta) {
    size_t idx4 = (size_t)blockIdx.x * 256 + threadIdx.x;
    size_t flat = idx4 * 4;
    int ch = (int)((flat >> 10) & 511);
    float S = sums[ch], S2 = sums[CH + ch];
    const float invcnt = 1.0f / (BATCH * NSP);
    float mean = S * invcnt;
    float var = S2 * invcnt - mean * mean;
    float sc = rsqrtf(var + EPSV) * gamma[ch];
    float bi = beta[ch] - mean * sc;
    float4 wv = *(float4*)(out + flat);
    float4 xv = *(const float4*)(x + flat);
    wv.x = wv.x * sc + bi + xv.x;
    wv.y = wv.y * sc + bi + xv.y;
    wv.z = wv.z * sc + bi + xv.z;
    wv.w = wv.w * sc + bi + xv.w;
    *(float4*)(out + flat) = wv;
}

// ---------------------------------------------------------------------------
extern "C" void kernel_launch(void* const* d_in, const int* in_sizes, int n_in,
                              void* d_out, int out_size, void* d_ws, size_t ws_size,
                              hipStream_t stream) {
    const float* x     = (const float*)d_in[0];
    const float* Wg    = (const float*)d_in[1];
    const float* bg    = (const float*)d_in[2];
    const float* Wt    = (const float*)d_in[3];
    const float* bt    = (const float*)d_in[4];
    const float* Wp    = (const float*)d_in[5];
    const float* bp    = (const float*)d_in[6];
    const float* Wz    = (const float*)d_in[7];
    const float* bz    = (const float*)d_in[8];
    const float* gamma = (const float*)d_in[9];
    const float* beta  = (const float*)d_in[10];
    float* out = (float*)d_out;

    char* ws = (char*)d_ws;
    bf16*  y_t   = (bf16*)(ws);                   // [32][4][1024][64]  16,777,216 B
    bf16*  g_t   = (bf16*)(ws + 16777216);        // blocked V tiles   16,777,216 B
    bf16*  wc    = (bf16*)(ws + 33554432);        // [8][768][64]         786,432 B
    bf16*  wzb   = (bf16*)(ws + 34340864);        // [4][512][64]         262,144 B
    float* sums  = (float*)(ws + 34603008);       // [2][512]               4,096 B

    char* ob = (char*)d_out;                      // d_out as scratch until out_gemm
    bf16* xb    = (bf16*)(ob);                    // [32][8][1024][64] 33,554,432 B
    bf16* theta = (bf16*)(ob + 33554432);         // [32][1024][256]   16,777,216 B
    bf16* phi_t = (bf16*)(ob + 50331648);         // blocked K tiles   16,777,216 B

    prep_weights<<<dim3(2048), dim3(256), 0, stream>>>(Wg, Wt, Wp, Wz, wc, wzb, sums);
    transpose_x<<<dim3(16, 8, 32), dim3(256), 0, stream>>>(x, xb);
    proj_gemm<<<dim3(6, 8, 32), dim3(256), 0, stream>>>(xb, wc, bt, bp, bg, theta, phi_t, g_t);
    attn_kernel<<<dim3(512), dim3(256), 0, stream>>>(theta, phi_t, g_t, y_t);
    out_gemm<<<dim3(8, 4, 32), dim3(256), 0, stream>>>(y_t, wzb, bz, out, sums);
    bn_finalize<<<dim3(16384), dim3(256), 0, stream>>>(out, x, sums, gamma, beta);
}

// Round 7
// 273.058 us; speedup vs baseline: 1.0619x; 1.0619x over previous
//
#include <hip/hip_runtime.h>
#include <math.h>

typedef __bf16 bf16;
typedef __bf16 bf16x8 __attribute__((ext_vector_type(8)));
typedef float f32x4 __attribute__((ext_vector_type(4)));
typedef unsigned short u16;
typedef unsigned int u32;

constexpr int BATCH = 32;
constexpr int CH    = 512;   // C
constexpr int CI    = 256;   // C/2
constexpr int NSP   = 1024;  // H*W
constexpr int OCH   = 768;   // 3*CI (theta|phi|g concat)
constexpr float EPSV = 1e-5f;
constexpr float LOG2E = 1.4426950408889634f;

#if __has_builtin(__builtin_amdgcn_exp2f)
#define EXP2F(x) __builtin_amdgcn_exp2f(x)
#else
#define EXP2F(x) exp2f(x)
#endif

// async global->LDS, 16B per lane: LDS dest = wave-uniform base + lane*16
__device__ __forceinline__ void gload_lds16(const bf16* g, bf16* l) {
    __builtin_amdgcn_global_load_lds(
        (const __attribute__((address_space(1))) void*)g,
        (__attribute__((address_space(3))) void*)l, 16, 0, 0);
}

__device__ __forceinline__ u32 pack_bf16(float a, float b) {
    union { bf16 h; u16 u; } ca, cb;
    ca.h = (bf16)a; cb.h = (bf16)b;
    return (u32)ca.u | ((u32)cb.u << 16);
}

// ---------------------------------------------------------------------------
// K0a: weights -> bf16, k-blocked tiles of 64. Also zeroes the BN sums.
// ---------------------------------------------------------------------------
__global__ void prep_weights(const float* __restrict__ Wg, const float* __restrict__ Wt,
                             const float* __restrict__ Wp, const float* __restrict__ Wz,
                             bf16* __restrict__ wc, bf16* __restrict__ wz,
                             float* __restrict__ sums) {
    int tid = blockIdx.x * 256 + threadIdx.x;
    if (tid < 1024) sums[tid] = 0.0f;
    if (tid < OCH * CH) {
        int r = tid / CH, c = tid % CH;
        float v;
        if (r < 256)      v = Wt[r * CH + c];
        else if (r < 512) v = Wp[(r - 256) * CH + c];
        else              v = Wg[(r - 512) * CH + c];
        wc[(size_t)(c >> 6) * (OCH * 64) + r * 64 + (c & 63)] = (bf16)v;
    } else {
        int t2 = tid - OCH * CH;
        if (t2 < CH * CI) {
            int r = t2 / CI, o = t2 % CI;
            wz[(size_t)(o >> 6) * (CH * 64) + r * 64 + (o & 63)] = (bf16)Wz[r * CI + o];
        }
    }
}

// ---------------------------------------------------------------------------
// K0b: x [b][c][n] fp32 -> xb [b][kt][n][64] bf16 (64x64 LDS transpose tiles)
// ---------------------------------------------------------------------------
__global__ void transpose_x(const float* __restrict__ x, bf16* __restrict__ xb) {
    __shared__ bf16 tile[64][64];
    int b = blockIdx.z, kt = blockIdx.y, nb = blockIdx.x;
    int t = threadIdx.x;
    {
        int c_loc = t >> 2;
        int nq = t & 3;
        const float* src = x + ((size_t)b * CH + kt * 64 + c_loc) * NSP + nb * 64 + nq * 16;
        float vv[16];
        *(float4*)(vv + 0)  = *(const float4*)(src + 0);
        *(float4*)(vv + 4)  = *(const float4*)(src + 4);
        *(float4*)(vv + 8)  = *(const float4*)(src + 8);
        *(float4*)(vv + 12) = *(const float4*)(src + 12);
        int nbase = nq * 16;
        #pragma unroll
        for (int i = 0; i < 16; ++i) tile[nbase + i][c_loc] = (bf16)vv[i];
    }
    __syncthreads();
    {
        int n_loc = t >> 2;
        int cq = t & 3;
        bf16* dst = xb + ((((size_t)b * 8 + kt) * NSP) + nb * 64 + n_loc) * 64 + cq * 16;
        *(uint4*)(dst)     = *(const uint4*)&tile[n_loc][cq * 16];
        *(uint4*)(dst + 8) = *(const uint4*)&tile[n_loc][cq * 16 + 8];
    }
}

// ---------------------------------------------------------------------------
// K1: fused projection GEMM.  R7: staging via global_load_lds width-16
// (m97 structure: linear [128][64] LDS, 2-barrier K-loop, no VGPR roundtrip).
//   theta -> linear [b][n][ci], PRE-SCALED by log2(e);
//   phi/g -> BLOCKED MFMA-fragment tiles; V (g) kv-order PERMUTED (R4).
// ---------------------------------------------------------------------------
__launch_bounds__(256, 3)
__global__ void proj_gemm(const bf16* __restrict__ xb, const bf16* __restrict__ wc,
                          const float* __restrict__ bt, const float* __restrict__ bp,
                          const float* __restrict__ bg,
                          bf16* __restrict__ theta, bf16* __restrict__ phi_t,
                          bf16* __restrict__ gt_t) {
    // As [128][64] @0 (16 KB) | Bs [128][64] @16K ; g-epilogue T overlays (34.8 KB)
    __shared__ __align__(16) char smm[36864];
    bf16* As = (bf16*)smm;
    bf16* Bs = (bf16*)(smm + 16384);
    int b = blockIdx.z;
    int n0 = blockIdx.y * 128;
    int oc0 = blockIdx.x * 128;
    int t = threadIdx.x, lane = t & 63, w = t >> 6;
    int wm = w >> 1, wn = w & 1;
    int l15 = lane & 15, quad = lane >> 4;

    f32x4 acc[4][4] = {};
    for (int kt = 0; kt < 8; ++kt) {
        __syncthreads();   // prior tile's reads done before overwrite
        const bf16* asrc = xb + ((((size_t)b * 8 + kt) * NSP) + n0) * 64 + w * 2048 + lane * 8;
        const bf16* bsrc = wc + ((size_t)kt * OCH + oc0) * 64 + w * 2048 + lane * 8;
        bf16* ad = As + w * 2048;
        bf16* bd = Bs + w * 2048;
        #pragma unroll
        for (int i = 0; i < 4; ++i) {
            gload_lds16(asrc + i * 512, ad + i * 512);
            gload_lds16(bsrc + i * 512, bd + i * 512);
        }
        __syncthreads();   // drains vmcnt -> staged tiles visible
        #pragma unroll
        for (int kc = 0; kc < 2; ++kc) {
            bf16x8 af[4], bfv[4];
            #pragma unroll
            for (int i = 0; i < 4; ++i) {
                af[i]  = *(const bf16x8*)&As[(wm * 64 + i * 16 + l15) * 64 + kc * 32 + quad * 8];
                bfv[i] = *(const bf16x8*)&Bs[(wn * 64 + i * 16 + l15) * 64 + kc * 32 + quad * 8];
            }
            #pragma unroll
            for (int i = 0; i < 4; ++i)
                #pragma unroll
                for (int j = 0; j < 4; ++j)
                    acc[i][j] = __builtin_amdgcn_mfma_f32_16x16x32_bf16(af[i], bfv[j], acc[i][j], 0, 0, 0);
        }
    }
    if (oc0 < 256) {
        // theta: linear [b][n][ci], scaled by log2(e) so attn uses exp2
        #pragma unroll
        for (int j = 0; j < 4; ++j) {
            int och = oc0 + wn * 64 + j * 16 + l15;
            float bv = bt[och];
            #pragma unroll
            for (int i = 0; i < 4; ++i) {
                int nrow = n0 + wm * 64 + i * 16 + quad * 4;
                bf16* p = theta + ((size_t)b * NSP + nrow) * CI + och;
                #pragma unroll
                for (int r = 0; r < 4; ++r)
                    p[(size_t)r * CI] = (bf16)((acc[i][j][r] + bv) * LOG2E);
            }
        }
    } else if (oc0 < 512) {
        // phi: blocked K-tiles
        bf16* dstb = phi_t + (size_t)b * 262144;
        #pragma unroll
        for (int j = 0; j < 4; ++j) {
            int och = (oc0 - 256) + wn * 64 + j * 16 + l15;
            float bv = bp[och];
            int kc = och >> 5, qd = (och >> 3) & 3, e = och & 7;
            #pragma unroll
            for (int i = 0; i < 4; ++i) {
                int nrow = n0 + wm * 64 + i * 16 + quad * 4;   // row16 base = quad*4
                int kt = nrow >> 5, h = (nrow >> 4) & 1;
                bf16* p = dstb + (size_t)kt * 8192 +
                          (size_t)(((h * 8 + kc) * 64 + qd * 16 + quad * 4) * 8) + e;
                #pragma unroll
                for (int r = 0; r < 4; ++r)
                    p[r * 8] = (bf16)(acc[i][j][r] + bv);
            }
        }
    } else {
        // g: transpose tile in LDS, then write PERMUTED blocked V-tiles.
        constexpr int LT = 136;
        int obase = oc0 - 512;
        __syncthreads();
        bf16* T = (bf16*)smm;
        #pragma unroll
        for (int j = 0; j < 4; ++j) {
            int och = wn * 64 + j * 16 + l15;
            float bv = bg[obase + och];
            #pragma unroll
            for (int i = 0; i < 4; ++i) {
                int nl = wm * 64 + i * 16 + quad * 4;
                bf16 tmp[4];
                #pragma unroll
                for (int r = 0; r < 4; ++r) tmp[r] = (bf16)(acc[i][j][r] + bv);
                *(uint2*)&T[och * LT + nl] = *(const uint2*)tmp;
            }
        }
        __syncthreads();
        bf16* dstb = gt_t + (size_t)b * 262144;
        for (int s = t; s < 2048; s += 256) {
            int row = s >> 4, part = s & 15;
            int o = obase + row;
            int kglob = n0 + part * 8;
            int kt = kglob >> 5, qd = (kglob >> 3) & 3;
            int qa = (2 * qd) & 3, qb = (2 * qd + 1) & 3;
            int jb = (qd & 2) * 2;             // 0 or 4
            bf16* base = dstb + (size_t)kt * 8192 + (size_t)((o >> 4) * 512 + (o & 15) * 8);
            *(uint2*)(base + qa * 128 + jb) = *(const uint2*)&T[row * LT + part * 8];
            *(uint2*)(base + qb * 128 + jb) = *(const uint2*)&T[row * LT + part * 8 + 4];
        }
    }
}

// ---------------------------------------------------------------------------
// K2: fused attention (R6 structure, unchanged — isolates the GEMM change).
// ---------------------------------------------------------------------------

#define STAGE(TILE, KDST, VDST) {                                           \
    const bf16* ksrc_ = ph_b + (size_t)(TILE) * 8192;                       \
    const bf16* vsrc_ = gt_b + (size_t)(TILE) * 8192;                       \
    bf16* kd_ = (KDST) + w * 2048;                                          \
    bf16* vd_ = (VDST) + w * 2048;                                          \
    _Pragma("unroll")                                                       \
    for (int i_ = 0; i_ < 4; ++i_) {                                        \
        gload_lds16(ksrc_ + i_ * 512, kd_ + i_ * 512);                      \
        gload_lds16(vsrc_ + i_ * 512, vd_ + i_ * 512);                      \
    } }

#define QKT(S0, S1, KBUF) {                                                 \
    S0 = (f32x4){}; S1 = (f32x4){};                                         \
    __builtin_amdgcn_s_setprio(1);                                          \
    _Pragma("unroll")                                                       \
    for (int kc_ = 0; kc_ < 8; ++kc_) {                                     \
        bf16x8 kf0_ = *(const bf16x8*)((KBUF) + kc_ * 512 + lane * 8);      \
        bf16x8 kf1_ = *(const bf16x8*)((KBUF) + 4096 + kc_ * 512 + lane * 8);\
        S0 = __builtin_amdgcn_mfma_f32_16x16x32_bf16(kf0_, qf[kc_], S0, 0, 0, 0); \
        S1 = __builtin_amdgcn_mfma_f32_16x16x32_bf16(kf1_, qf[kc_], S1, 0, 0, 0); \
    }                                                                       \
    __builtin_amdgcn_s_setprio(0); }

#define SMPV(S0, S1, VBUF) {                                                \
    float c_ = fmaxf(fmaxf(fmaxf(S0[0], S0[1]), fmaxf(S0[2], S0[3])),       \
                     fmaxf(fmaxf(S1[0], S1[1]), fmaxf(S1[2], S1[3])));      \
    c_ = fmaxf(c_, __shfl_xor(c_, 16));                                     \
    c_ = fmaxf(c_, __shfl_xor(c_, 32));                                     \
    int flag_ = (c_ > m + 11.5424f) ? 1 : 0;                                \
    if (__any(flag_)) {                                                     \
        float mn_ = fmaxf(m, c_);                                           \
        float al_ = EXP2F(m - mn_);                                         \
        m = mn_; ps *= al_;                                                 \
        float a0_ = __shfl(al_, quad * 4 + 0);                              \
        float a1_ = __shfl(al_, quad * 4 + 1);                              \
        float a2_ = __shfl(al_, quad * 4 + 2);                              \
        float a3_ = __shfl(al_, quad * 4 + 3);                              \
        _Pragma("unroll")                                                   \
        for (int nt_ = 0; nt_ < 16; ++nt_) {                                \
            oacc[nt_][0] *= a0_; oacc[nt_][1] *= a1_;                       \
            oacc[nt_][2] *= a2_; oacc[nt_][3] *= a3_;                       \
        } }                                                                 \
    float p0_ = EXP2F(S0[0] - m), p1_ = EXP2F(S0[1] - m);                   \
    float p2_ = EXP2F(S0[2] - m), p3_ = EXP2F(S0[3] - m);                   \
    float p4_ = EXP2F(S1[0] - m), p5_ = EXP2F(S1[1] - m);                   \
    float p6_ = EXP2F(S1[2] - m), p7_ = EXP2F(S1[3] - m);                   \
    ps += ((p0_ + p1_) + (p2_ + p3_)) + ((p4_ + p5_) + (p6_ + p7_));        \
    bf16x8 pf_;                                                             \
    { union { u32 u[4]; bf16x8 v; } cvt_;                                   \
      cvt_.u[0] = pack_bf16(p0_, p1_); cvt_.u[1] = pack_bf16(p2_, p3_);     \
      cvt_.u[2] = pack_bf16(p4_, p5_); cvt_.u[3] = pack_bf16(p6_, p7_);     \
      pf_ = cvt_.v; }                                                       \
    __builtin_amdgcn_s_setprio(1);                                          \
    _Pragma("unroll")                                                       \
    for (int nt_ = 0; nt_ < 16; ++nt_) {                                    \
        bf16x8 vf_ = *(const bf16x8*)((VBUF) + nt_ * 512 + lane * 8);       \
        oacc[nt_] = __builtin_amdgcn_mfma_f32_16x16x32_bf16(pf_, vf_, oacc[nt_], 0, 0, 0); \
    }                                                                       \
    __builtin_amdgcn_s_setprio(0); }

__launch_bounds__(256, 2)
__global__ void attn_kernel(const bf16* __restrict__ theta, const bf16* __restrict__ phi_t,
                            const bf16* __restrict__ gt_t, bf16* __restrict__ y) {
    // layout: KB0 @0 | KB1 @16K | V0 @32K | V1 @48K | V2 @64K   (80 KB)
    __shared__ __align__(16) char smem[81920];

    int id = blockIdx.x;
    int j = id >> 3;
    int qt = j & 15;
    int b = (id & 7) + 8 * (j >> 4);

    int t = threadIdx.x, lane = t & 63, w = t >> 6;
    int l15 = lane & 15, quad = lane >> 4;

    const bf16* ph_b = phi_t + (size_t)b * 262144 + w * 2048 + lane * 8;
    const bf16* gt_b = gt_t + (size_t)b * 262144 + w * 2048 + lane * 8;

    // Q fragments directly from global (one-time); lane->q, quad->d-chunk
    bf16x8 qf[8];
    {
        const bf16* qrow = theta + ((size_t)b * NSP + qt * 64 + w * 16 + l15) * CI;
        #pragma unroll
        for (int kc = 0; kc < 8; ++kc)
            qf[kc] = *(const bf16x8*)(qrow + kc * 32 + quad * 8);
    }

    bf16* KB0 = (bf16*)smem;
    bf16* KB1 = (bf16*)(smem + 16384);
    bf16* Va  = (bf16*)(smem + 32768);
    bf16* Vb  = (bf16*)(smem + 49152);
    bf16* Vc  = (bf16*)(smem + 65536);

    // prologue: K[0]->KB0, V[0]->Va, K[1]->KB1, V[1]->Vb
    STAGE(0, KB0, Va);
    STAGE(1, KB1, Vb);
    __syncthreads();

    f32x4 oacc[16] = {};
    float m = -1e30f;
    float ps = 0.0f;
    f32x4 sA0, sA1, sB0, sB1;

    QKT(sA0, sA1, KB0);          // S(tile 0)
    __syncthreads();             // protect KB0 before iter-0 restage

    for (int kt2 = 0; kt2 < 32; kt2 += 2) {
        // ---- even body: kt = kt2 ----
        if (kt2 < 30) STAGE(kt2 + 2, KB0, Vc);
        QKT(sB0, sB1, KB1);      // S(kt2+1), overlaps softmax below
        SMPV(sA0, sA1, Va);      // softmax+PV for tile kt2
        __syncthreads();
        { bf16* tmp = Va; Va = Vb; Vb = Vc; Vc = tmp; }
        // ---- odd body: kt = kt2 + 1 ----
        if (kt2 < 30) {
            STAGE(kt2 + 3, KB1, Vc);
            QKT(sA0, sA1, KB0);  // S(kt2+2)
        }
        SMPV(sB0, sB1, Va);      // softmax+PV for tile kt2+1
        __syncthreads();
        { bf16* tmp = Va; Va = Vb; Vb = Vc; Vc = tmp; }
    }

    // final denom: combine the 4 quad-partials for each q, then redistribute
    ps += __shfl_xor(ps, 16);
    ps += __shfl_xor(ps, 32);
    float inv = 1.0f / ps;
    float inv0 = __shfl(inv, quad * 4 + 0);
    float inv1 = __shfl(inv, quad * 4 + 1);
    float inv2 = __shfl(inv, quad * 4 + 2);
    float inv3 = __shfl(inv, quad * 4 + 3);

    int nrow = qt * 64 + w * 16 + quad * 4;
    #pragma unroll
    for (int nt = 0; nt < 16; ++nt) {
        int o = nt * 16 + l15;
        bf16* dst = y + ((((size_t)b * 4 + (o >> 6)) * NSP) + nrow) * 64 + (o & 63);
        dst[0]           = (bf16)(oacc[nt][0] * inv0);
        dst[(size_t)64]  = (bf16)(oacc[nt][1] * inv1);
        dst[(size_t)128] = (bf16)(oacc[nt][2] * inv2);
        dst[(size_t)192] = (bf16)(oacc[nt][3] * inv3);
    }
}

// ---------------------------------------------------------------------------
// K3: output GEMM + fused BN stats.  R7: global_load_lds staging (m97-style),
// linear [128][64] LDS. LDS cross-wave combine -> 128 atomic pairs per block.
// ---------------------------------------------------------------------------
__launch_bounds__(256, 4)
__global__ void out_gemm(const bf16* __restrict__ y, const bf16* __restrict__ wz,
                         const float* __restrict__ bz, float* __restrict__ wy,
                         float* __restrict__ sums) {
    __shared__ __align__(16) bf16 As[128 * 64];
    __shared__ __align__(16) bf16 Bs[128 * 64];
    __shared__ float redS[128][2], redS2[128][2];
    int b = blockIdx.z;
    int co0 = blockIdx.y * 128;
    int n0 = blockIdx.x * 128;
    int t = threadIdx.x, lane = t & 63, w = t >> 6;
    int wm = w >> 1, wn = w & 1;
    int l15 = lane & 15, quad = lane >> 4;

    f32x4 acc[4][4] = {};
    for (int kt = 0; kt < 4; ++kt) {
        __syncthreads();
        const bf16* asrc = wz + ((size_t)kt * CH + co0) * 64 + w * 2048 + lane * 8;
        const bf16* bsrc = y + ((((size_t)b * 4 + kt) * NSP) + n0) * 64 + w * 2048 + lane * 8;
        bf16* ad = As + w * 2048;
        bf16* bd = Bs + w * 2048;
        #pragma unroll
        for (int i = 0; i < 4; ++i) {
            gload_lds16(asrc + i * 512, ad + i * 512);
            gload_lds16(bsrc + i * 512, bd + i * 512);
        }
        __syncthreads();
        #pragma unroll
        for (int kc = 0; kc < 2; ++kc) {
            bf16x8 af[4], bfv[4];
            #pragma unroll
            for (int i = 0; i < 4; ++i) {
                af[i]  = *(const bf16x8*)&As[(wm * 64 + i * 16 + l15) * 64 + kc * 32 + quad * 8];
                bfv[i] = *(const bf16x8*)&Bs[(wn * 64 + i * 16 + l15) * 64 + kc * 32 + quad * 8];
            }
            #pragma unroll
            for (int i = 0; i < 4; ++i)
                #pragma unroll
                for (int j = 0; j < 4; ++j)
                    acc[i][j] = __builtin_amdgcn_mfma_f32_16x16x32_bf16(af[i], bfv[j], acc[i][j], 0, 0, 0);
        }
    }
    #pragma unroll
    for (int i = 0; i < 4; ++i) {
        int cbase = co0 + wm * 64 + i * 16 + quad * 4;
        #pragma unroll
        for (int r = 0; r < 4; ++r) {
            int c = cbase + r;
            float bv = bz[c];
            float s = 0.f, s2 = 0.f;
            #pragma unroll
            for (int jj = 0; jj < 4; ++jj) {
                int n = n0 + wn * 64 + jj * 16 + l15;
                float v = acc[i][jj][r] + bv;
                wy[((size_t)b * CH + c) * NSP + n] = v;
                s += v; s2 += v * v;
            }
            s  += __shfl_xor(s, 1);  s2 += __shfl_xor(s2, 1);
            s  += __shfl_xor(s, 2);  s2 += __shfl_xor(s2, 2);
            s  += __shfl_xor(s, 4);  s2 += __shfl_xor(s2, 4);
            s  += __shfl_xor(s, 8);  s2 += __shfl_xor(s2, 8);
            if (l15 == 0) {
                int cl = wm * 64 + i * 16 + quad * 4 + r;
                redS[cl][wn]  = s;
                redS2[cl][wn] = s2;
            }
        }
    }
    __syncthreads();
    if (t < 128) {
        atomicAdd(&sums[co0 + t],      redS[t][0] + redS[t][1]);
        atomicAdd(&sums[CH + co0 + t], redS2[t][0] + redS2[t][1]);
    }
}

// ---------------------------------------------------------------------------
// K4: BN normalize + affine + residual, in-place on d_out. float4.
// ---------------------------------------------------------------------------
__global__ void bn_finalize(float* __restrict__ out, const float* __restrict__ x,
                            const float* __restrict__ sums,
                            const float* __restrict__ gamma, const float* __restrict__ beta) {
    size_t idx4 = (size_t)blockIdx.x * 256 + threadIdx.x;
    size_t flat = idx4 * 4;
    int ch = (int)((flat >> 10) & 511);
    float S = sums[ch], S2 = sums[CH + ch];
    const float invcnt = 1.0f / (BATCH * NSP);
    float mean = S * invcnt;
    float var = S2 * invcnt - mean * mean;
    float sc = rsqrtf(var + EPSV) * gamma[ch];
    float bi = beta[ch] - mean * sc;
    float4 wv = *(float4*)(out + flat);
    float4 xv = *(const float4*)(x + flat);
    wv.x = wv.x * sc + bi + xv.x;
    wv.y = wv.y * sc + bi + xv.y;
    wv.z = wv.z * sc + bi + xv.z;
    wv.w = wv.w * sc + bi + xv.w;
    *(float4*)(out + flat) = wv;
}

// ---------------------------------------------------------------------------
extern "C" void kernel_launch(void* const* d_in, const int* in_sizes, int n_in,
                              void* d_out, int out_size, void* d_ws, size_t ws_size,
                              hipStream_t stream) {
    const float* x     = (const float*)d_in[0];
    const float* Wg    = (const float*)d_in[1];
    const float* bg    = (const float*)d_in[2];
    const float* Wt    = (const float*)d_in[3];
    const float* bt    = (const float*)d_in[4];
    const float* Wp    = (const float*)d_in[5];
    const float* bp    = (const float*)d_in[6];
    const float* Wz    = (const float*)d_in[7];
    const float* bz    = (const float*)d_in[8];
    const float* gamma = (const float*)d_in[9];
    const float* beta  = (const float*)d_in[10];
    float* out = (float*)d_out;

    char* ws = (char*)d_ws;
    bf16*  y_t   = (bf16*)(ws);                   // [32][4][1024][64]  16,777,216 B
    bf16*  g_t   = (bf16*)(ws + 16777216);        // blocked V tiles   16,777,216 B
    bf16*  wc    = (bf16*)(ws + 33554432);        // [8][768][64]         786,432 B
    bf16*  wzb   = (bf16*)(ws + 34340864);        // [4][512][64]         262,144 B
    float* sums  = (float*)(ws + 34603008);       // [2][512]               4,096 B

    char* ob = (char*)d_out;                      // d_out as scratch until out_gemm
    bf16* xb    = (bf16*)(ob);                    // [32][8][1024][64] 33,554,432 B
    bf16* theta = (bf16*)(ob + 33554432);         // [32][1024][256]   16,777,216 B
    bf16* phi_t = (bf16*)(ob + 50331648);         // blocked K tiles   16,777,216 B

    prep_weights<<<dim3(2048), dim3(256), 0, stream>>>(Wg, Wt, Wp, Wz, wc, wzb, sums);
    transpose_x<<<dim3(16, 8, 32), dim3(256), 0, stream>>>(x, xb);
    proj_gemm<<<dim3(6, 8, 32), dim3(256), 0, stream>>>(xb, wc, bt, bp, bg, theta, phi_t, g_t);
    attn_kernel<<<dim3(512), dim3(256), 0, stream>>>(theta, phi_t, g_t, y_t);
    out_gemm<<<dim3(8, 4, 32), dim3(256), 0, stream>>>(y_t, wzb, bz, out, sums);
    bn_finalize<<<dim3(16384), dim3(256), 0, stream>>>(out, x, sums, gamma, beta);
}

// Round 8
// 269.159 us; speedup vs baseline: 1.0773x; 1.0145x over previous
//
#include <hip/hip_runtime.h>
#include <math.h>

typedef __bf16 bf16;
typedef __bf16 bf16x8 __attribute__((ext_vector_type(8)));
typedef float f32x4 __attribute__((ext_vector_type(4)));
typedef unsigned short u16;
typedef unsigned int u32;

constexpr int BATCH = 32;
constexpr int CH    = 512;   // C
constexpr int CI    = 256;   // C/2
constexpr int NSP   = 1024;  // H*W
constexpr int OCH   = 768;   // 3*CI (theta|phi|g concat)
constexpr float EPSV = 1e-5f;
constexpr float LOG2E = 1.4426950408889634f;

#if __has_builtin(__builtin_amdgcn_exp2f)
#define EXP2F(x) __builtin_amdgcn_exp2f(x)
#else
#define EXP2F(x) exp2f(x)
#endif

// async global->LDS, 16B per lane: LDS dest = wave-uniform base + lane*16
__device__ __forceinline__ void gload_lds16(const bf16* g, bf16* l) {
    __builtin_amdgcn_global_load_lds(
        (const __attribute__((address_space(1))) void*)g,
        (__attribute__((address_space(3))) void*)l, 16, 0, 0);
}

__device__ __forceinline__ u32 pack_bf16(float a, float b) {
    union { bf16 h; u16 u; } ca, cb;
    ca.h = (bf16)a; cb.h = (bf16)b;
    return (u32)ca.u | ((u32)cb.u << 16);
}

// ---------------------------------------------------------------------------
// K0a: weights -> bf16, k-blocked tiles of 64. Also zeroes the BN sums.
// ---------------------------------------------------------------------------
__global__ void prep_weights(const float* __restrict__ Wg, const float* __restrict__ Wt,
                             const float* __restrict__ Wp, const float* __restrict__ Wz,
                             bf16* __restrict__ wc, bf16* __restrict__ wz,
                             float* __restrict__ sums) {
    int tid = blockIdx.x * 256 + threadIdx.x;
    if (tid < 1024) sums[tid] = 0.0f;
    if (tid < OCH * CH) {
        int r = tid / CH, c = tid % CH;
        float v;
        if (r < 256)      v = Wt[r * CH + c];
        else if (r < 512) v = Wp[(r - 256) * CH + c];
        else              v = Wg[(r - 512) * CH + c];
        wc[(size_t)(c >> 6) * (OCH * 64) + r * 64 + (c & 63)] = (bf16)v;
    } else {
        int t2 = tid - OCH * CH;
        if (t2 < CH * CI) {
            int r = t2 / CI, o = t2 % CI;
            wz[(size_t)(o >> 6) * (CH * 64) + r * 64 + (o & 63)] = (bf16)Wz[r * CI + o];
        }
    }
}

// ---------------------------------------------------------------------------
// K0b: x [b][c][n] fp32 -> xb [b][kt][n][64] bf16 (64x64 LDS transpose tiles)
// ---------------------------------------------------------------------------
__global__ void transpose_x(const float* __restrict__ x, bf16* __restrict__ xb) {
    __shared__ bf16 tile[64][64];
    int b = blockIdx.z, kt = blockIdx.y, nb = blockIdx.x;
    int t = threadIdx.x;
    {
        int c_loc = t >> 2;
        int nq = t & 3;
        const float* src = x + ((size_t)b * CH + kt * 64 + c_loc) * NSP + nb * 64 + nq * 16;
        float vv[16];
        *(float4*)(vv + 0)  = *(const float4*)(src + 0);
        *(float4*)(vv + 4)  = *(const float4*)(src + 4);
        *(float4*)(vv + 8)  = *(const float4*)(src + 8);
        *(float4*)(vv + 12) = *(const float4*)(src + 12);
        int nbase = nq * 16;
        #pragma unroll
        for (int i = 0; i < 16; ++i) tile[nbase + i][c_loc] = (bf16)vv[i];
    }
    __syncthreads();
    {
        int n_loc = t >> 2;
        int cq = t & 3;
        bf16* dst = xb + ((((size_t)b * 8 + kt) * NSP) + nb * 64 + n_loc) * 64 + cq * 16;
        *(uint4*)(dst)     = *(const uint4*)&tile[n_loc][cq * 16];
        *(uint4*)(dst + 8) = *(const uint4*)&tile[n_loc][cq * 16 + 8];
    }
}

// ---------------------------------------------------------------------------
// K1: fused projection GEMM (R7 structure: global_load_lds staging).
//   theta -> linear [b][n][ci], PRE-SCALED by log2(e);
//   phi/g -> BLOCKED MFMA-fragment tiles; V (g) kv-order PERMUTED (R4).
// ---------------------------------------------------------------------------
__launch_bounds__(256, 3)
__global__ void proj_gemm(const bf16* __restrict__ xb, const bf16* __restrict__ wc,
                          const float* __restrict__ bt, const float* __restrict__ bp,
                          const float* __restrict__ bg,
                          bf16* __restrict__ theta, bf16* __restrict__ phi_t,
                          bf16* __restrict__ gt_t) {
    // As [128][64] @0 (16 KB) | Bs [128][64] @16K ; g-epilogue T overlays (34.8 KB)
    __shared__ __align__(16) char smm[36864];
    bf16* As = (bf16*)smm;
    bf16* Bs = (bf16*)(smm + 16384);
    int b = blockIdx.z;
    int n0 = blockIdx.y * 128;
    int oc0 = blockIdx.x * 128;
    int t = threadIdx.x, lane = t & 63, w = t >> 6;
    int wm = w >> 1, wn = w & 1;
    int l15 = lane & 15, quad = lane >> 4;

    f32x4 acc[4][4] = {};
    for (int kt = 0; kt < 8; ++kt) {
        __syncthreads();   // prior tile's reads done before overwrite
        const bf16* asrc = xb + ((((size_t)b * 8 + kt) * NSP) + n0) * 64 + w * 2048 + lane * 8;
        const bf16* bsrc = wc + ((size_t)kt * OCH + oc0) * 64 + w * 2048 + lane * 8;
        bf16* ad = As + w * 2048;
        bf16* bd = Bs + w * 2048;
        #pragma unroll
        for (int i = 0; i < 4; ++i) {
            gload_lds16(asrc + i * 512, ad + i * 512);
            gload_lds16(bsrc + i * 512, bd + i * 512);
        }
        __syncthreads();   // drains vmcnt -> staged tiles visible
        #pragma unroll
        for (int kc = 0; kc < 2; ++kc) {
            bf16x8 af[4], bfv[4];
            #pragma unroll
            for (int i = 0; i < 4; ++i) {
                af[i]  = *(const bf16x8*)&As[(wm * 64 + i * 16 + l15) * 64 + kc * 32 + quad * 8];
                bfv[i] = *(const bf16x8*)&Bs[(wn * 64 + i * 16 + l15) * 64 + kc * 32 + quad * 8];
            }
            #pragma unroll
            for (int i = 0; i < 4; ++i)
                #pragma unroll
                for (int j = 0; j < 4; ++j)
                    acc[i][j] = __builtin_amdgcn_mfma_f32_16x16x32_bf16(af[i], bfv[j], acc[i][j], 0, 0, 0);
        }
    }
    if (oc0 < 256) {
        // theta: linear [b][n][ci], scaled by log2(e) so attn uses exp2
        #pragma unroll
        for (int j = 0; j < 4; ++j) {
            int och = oc0 + wn * 64 + j * 16 + l15;
            float bv = bt[och];
            #pragma unroll
            for (int i = 0; i < 4; ++i) {
                int nrow = n0 + wm * 64 + i * 16 + quad * 4;
                bf16* p = theta + ((size_t)b * NSP + nrow) * CI + och;
                #pragma unroll
                for (int r = 0; r < 4; ++r)
                    p[(size_t)r * CI] = (bf16)((acc[i][j][r] + bv) * LOG2E);
            }
        }
    } else if (oc0 < 512) {
        // phi: blocked K-tiles
        bf16* dstb = phi_t + (size_t)b * 262144;
        #pragma unroll
        for (int j = 0; j < 4; ++j) {
            int och = (oc0 - 256) + wn * 64 + j * 16 + l15;
            float bv = bp[och];
            int kc = och >> 5, qd = (och >> 3) & 3, e = och & 7;
            #pragma unroll
            for (int i = 0; i < 4; ++i) {
                int nrow = n0 + wm * 64 + i * 16 + quad * 4;   // row16 base = quad*4
                int kt = nrow >> 5, h = (nrow >> 4) & 1;
                bf16* p = dstb + (size_t)kt * 8192 +
                          (size_t)(((h * 8 + kc) * 64 + qd * 16 + quad * 4) * 8) + e;
                #pragma unroll
                for (int r = 0; r < 4; ++r)
                    p[r * 8] = (bf16)(acc[i][j][r] + bv);
            }
        }
    } else {
        // g: transpose tile in LDS, then write PERMUTED blocked V-tiles.
        constexpr int LT = 136;
        int obase = oc0 - 512;
        __syncthreads();
        bf16* T = (bf16*)smm;
        #pragma unroll
        for (int j = 0; j < 4; ++j) {
            int och = wn * 64 + j * 16 + l15;
            float bv = bg[obase + och];
            #pragma unroll
            for (int i = 0; i < 4; ++i) {
                int nl = wm * 64 + i * 16 + quad * 4;
                bf16 tmp[4];
                #pragma unroll
                for (int r = 0; r < 4; ++r) tmp[r] = (bf16)(acc[i][j][r] + bv);
                *(uint2*)&T[och * LT + nl] = *(const uint2*)tmp;
            }
        }
        __syncthreads();
        bf16* dstb = gt_t + (size_t)b * 262144;
        for (int s = t; s < 2048; s += 256) {
            int row = s >> 4, part = s & 15;
            int o = obase + row;
            int kglob = n0 + part * 8;
            int kt = kglob >> 5, qd = (kglob >> 3) & 3;
            int qa = (2 * qd) & 3, qb = (2 * qd + 1) & 3;
            int jb = (qd & 2) * 2;             // 0 or 4
            bf16* base = dstb + (size_t)kt * 8192 + (size_t)((o >> 4) * 512 + (o & 15) * 8);
            *(uint2*)(base + qa * 128 + jb) = *(const uint2*)&T[row * LT + part * 8];
            *(uint2*)(base + qb * 128 + jb) = *(const uint2*)&T[row * LT + part * 8 + 4];
        }
    }
}

// ---------------------------------------------------------------------------
// K2: fused attention (R6 structure, unchanged).
// ---------------------------------------------------------------------------

#define STAGE(TILE, KDST, VDST) {                                           \
    const bf16* ksrc_ = ph_b + (size_t)(TILE) * 8192;                       \
    const bf16* vsrc_ = gt_b + (size_t)(TILE) * 8192;                       \
    bf16* kd_ = (KDST) + w * 2048;                                          \
    bf16* vd_ = (VDST) + w * 2048;                                          \
    _Pragma("unroll")                                                       \
    for (int i_ = 0; i_ < 4; ++i_) {                                        \
        gload_lds16(ksrc_ + i_ * 512, kd_ + i_ * 512);                      \
        gload_lds16(vsrc_ + i_ * 512, vd_ + i_ * 512);                      \
    } }

#define QKT(S0, S1, KBUF) {                                                 \
    S0 = (f32x4){}; S1 = (f32x4){};                                         \
    __builtin_amdgcn_s_setprio(1);                                          \
    _Pragma("unroll")                                                       \
    for (int kc_ = 0; kc_ < 8; ++kc_) {                                     \
        bf16x8 kf0_ = *(const bf16x8*)((KBUF) + kc_ * 512 + lane * 8);      \
        bf16x8 kf1_ = *(const bf16x8*)((KBUF) + 4096 + kc_ * 512 + lane * 8);\
        S0 = __builtin_amdgcn_mfma_f32_16x16x32_bf16(kf0_, qf[kc_], S0, 0, 0, 0); \
        S1 = __builtin_amdgcn_mfma_f32_16x16x32_bf16(kf1_, qf[kc_], S1, 0, 0, 0); \
    }                                                                       \
    __builtin_amdgcn_s_setprio(0); }

#define SMPV(S0, S1, VBUF) {                                                \
    float c_ = fmaxf(fmaxf(fmaxf(S0[0], S0[1]), fmaxf(S0[2], S0[3])),       \
                     fmaxf(fmaxf(S1[0], S1[1]), fmaxf(S1[2], S1[3])));      \
    c_ = fmaxf(c_, __shfl_xor(c_, 16));                                     \
    c_ = fmaxf(c_, __shfl_xor(c_, 32));                                     \
    int flag_ = (c_ > m + 11.5424f) ? 1 : 0;                                \
    if (__any(flag_)) {                                                     \
        float mn_ = fmaxf(m, c_);                                           \
        float al_ = EXP2F(m - mn_);                                         \
        m = mn_; ps *= al_;                                                 \
        float a0_ = __shfl(al_, quad * 4 + 0);                              \
        float a1_ = __shfl(al_, quad * 4 + 1);                              \
        float a2_ = __shfl(al_, quad * 4 + 2);                              \
        float a3_ = __shfl(al_, quad * 4 + 3);                              \
        _Pragma("unroll")                                                   \
        for (int nt_ = 0; nt_ < 16; ++nt_) {                                \
            oacc[nt_][0] *= a0_; oacc[nt_][1] *= a1_;                       \
            oacc[nt_][2] *= a2_; oacc[nt_][3] *= a3_;                       \
        } }                                                                 \
    float p0_ = EXP2F(S0[0] - m), p1_ = EXP2F(S0[1] - m);                   \
    float p2_ = EXP2F(S0[2] - m), p3_ = EXP2F(S0[3] - m);                   \
    float p4_ = EXP2F(S1[0] - m), p5_ = EXP2F(S1[1] - m);                   \
    float p6_ = EXP2F(S1[2] - m), p7_ = EXP2F(S1[3] - m);                   \
    ps += ((p0_ + p1_) + (p2_ + p3_)) + ((p4_ + p5_) + (p6_ + p7_));        \
    bf16x8 pf_;                                                             \
    { union { u32 u[4]; bf16x8 v; } cvt_;                                   \
      cvt_.u[0] = pack_bf16(p0_, p1_); cvt_.u[1] = pack_bf16(p2_, p3_);     \
      cvt_.u[2] = pack_bf16(p4_, p5_); cvt_.u[3] = pack_bf16(p6_, p7_);     \
      pf_ = cvt_.v; }                                                       \
    __builtin_amdgcn_s_setprio(1);                                          \
    _Pragma("unroll")                                                       \
    for (int nt_ = 0; nt_ < 16; ++nt_) {                                    \
        bf16x8 vf_ = *(const bf16x8*)((VBUF) + nt_ * 512 + lane * 8);       \
        oacc[nt_] = __builtin_amdgcn_mfma_f32_16x16x32_bf16(pf_, vf_, oacc[nt_], 0, 0, 0); \
    }                                                                       \
    __builtin_amdgcn_s_setprio(0); }

__launch_bounds__(256, 2)
__global__ void attn_kernel(const bf16* __restrict__ theta, const bf16* __restrict__ phi_t,
                            const bf16* __restrict__ gt_t, bf16* __restrict__ y) {
    // layout: KB0 @0 | KB1 @16K | V0 @32K | V1 @48K | V2 @64K   (80 KB)
    __shared__ __align__(16) char smem[81920];

    int id = blockIdx.x;
    int j = id >> 3;
    int qt = j & 15;
    int b = (id & 7) + 8 * (j >> 4);

    int t = threadIdx.x, lane = t & 63, w = t >> 6;
    int l15 = lane & 15, quad = lane >> 4;

    const bf16* ph_b = phi_t + (size_t)b * 262144 + w * 2048 + lane * 8;
    const bf16* gt_b = gt_t + (size_t)b * 262144 + w * 2048 + lane * 8;

    // Q fragments directly from global (one-time); lane->q, quad->d-chunk
    bf16x8 qf[8];
    {
        const bf16* qrow = theta + ((size_t)b * NSP + qt * 64 + w * 16 + l15) * CI;
        #pragma unroll
        for (int kc = 0; kc < 8; ++kc)
            qf[kc] = *(const bf16x8*)(qrow + kc * 32 + quad * 8);
    }

    bf16* KB0 = (bf16*)smem;
    bf16* KB1 = (bf16*)(smem + 16384);
    bf16* Va  = (bf16*)(smem + 32768);
    bf16* Vb  = (bf16*)(smem + 49152);
    bf16* Vc  = (bf16*)(smem + 65536);

    // prologue: K[0]->KB0, V[0]->Va, K[1]->KB1, V[1]->Vb
    STAGE(0, KB0, Va);
    STAGE(1, KB1, Vb);
    __syncthreads();

    f32x4 oacc[16] = {};
    float m = -1e30f;
    float ps = 0.0f;
    f32x4 sA0, sA1, sB0, sB1;

    QKT(sA0, sA1, KB0);          // S(tile 0)
    __syncthreads();             // protect KB0 before iter-0 restage

    for (int kt2 = 0; kt2 < 32; kt2 += 2) {
        // ---- even body: kt = kt2 ----
        if (kt2 < 30) STAGE(kt2 + 2, KB0, Vc);
        QKT(sB0, sB1, KB1);      // S(kt2+1), overlaps softmax below
        SMPV(sA0, sA1, Va);      // softmax+PV for tile kt2
        __syncthreads();
        { bf16* tmp = Va; Va = Vb; Vb = Vc; Vc = tmp; }
        // ---- odd body: kt = kt2 + 1 ----
        if (kt2 < 30) {
            STAGE(kt2 + 3, KB1, Vc);
            QKT(sA0, sA1, KB0);  // S(kt2+2)
        }
        SMPV(sB0, sB1, Va);      // softmax+PV for tile kt2+1
        __syncthreads();
        { bf16* tmp = Va; Va = Vb; Vb = Vc; Vc = tmp; }
    }

    // final denom: combine the 4 quad-partials for each q, then redistribute
    ps += __shfl_xor(ps, 16);
    ps += __shfl_xor(ps, 32);
    float inv = 1.0f / ps;
    float inv0 = __shfl(inv, quad * 4 + 0);
    float inv1 = __shfl(inv, quad * 4 + 1);
    float inv2 = __shfl(inv, quad * 4 + 2);
    float inv3 = __shfl(inv, quad * 4 + 3);

    int nrow = qt * 64 + w * 16 + quad * 4;
    #pragma unroll
    for (int nt = 0; nt < 16; ++nt) {
        int o = nt * 16 + l15;
        bf16* dst = y + ((((size_t)b * 4 + (o >> 6)) * NSP) + nrow) * 64 + (o & 63);
        dst[0]           = (bf16)(oacc[nt][0] * inv0);
        dst[(size_t)64]  = (bf16)(oacc[nt][1] * inv1);
        dst[(size_t)128] = (bf16)(oacc[nt][2] * inv2);
        dst[(size_t)192] = (bf16)(oacc[nt][3] * inv3);
    }
}

// ---------------------------------------------------------------------------
// K3: output GEMM + fused BN stats. R8: templated wy store (f32 or bf16).
// Stats always from f32 accumulators. global_load_lds staging (R7).
// ---------------------------------------------------------------------------
template <bool U16>
__launch_bounds__(256, 4)
__global__ void out_gemm_t(const bf16* __restrict__ y, const bf16* __restrict__ wz,
                           const float* __restrict__ bz, float* __restrict__ wy,
                           bf16* __restrict__ wyb, float* __restrict__ sums) {
    __shared__ __align__(16) bf16 As[128 * 64];
    __shared__ __align__(16) bf16 Bs[128 * 64];
    __shared__ float redS[128][2], redS2[128][2];
    int b = blockIdx.z;
    int co0 = blockIdx.y * 128;
    int n0 = blockIdx.x * 128;
    int t = threadIdx.x, lane = t & 63, w = t >> 6;
    int wm = w >> 1, wn = w & 1;
    int l15 = lane & 15, quad = lane >> 4;

    f32x4 acc[4][4] = {};
    for (int kt = 0; kt < 4; ++kt) {
        __syncthreads();
        const bf16* asrc = wz + ((size_t)kt * CH + co0) * 64 + w * 2048 + lane * 8;
        const bf16* bsrc = y + ((((size_t)b * 4 + kt) * NSP) + n0) * 64 + w * 2048 + lane * 8;
        bf16* ad = As + w * 2048;
        bf16* bd = Bs + w * 2048;
        #pragma unroll
        for (int i = 0; i < 4; ++i) {
            gload_lds16(asrc + i * 512, ad + i * 512);
            gload_lds16(bsrc + i * 512, bd + i * 512);
        }
        __syncthreads();
        #pragma unroll
        for (int kc = 0; kc < 2; ++kc) {
            bf16x8 af[4], bfv[4];
            #pragma unroll
            for (int i = 0; i < 4; ++i) {
                af[i]  = *(const bf16x8*)&As[(wm * 64 + i * 16 + l15) * 64 + kc * 32 + quad * 8];
                bfv[i] = *(const bf16x8*)&Bs[(wn * 64 + i * 16 + l15) * 64 + kc * 32 + quad * 8];
            }
            #pragma unroll
            for (int i = 0; i < 4; ++i)
                #pragma unroll
                for (int j = 0; j < 4; ++j)
                    acc[i][j] = __builtin_amdgcn_mfma_f32_16x16x32_bf16(af[i], bfv[j], acc[i][j], 0, 0, 0);
        }
    }
    #pragma unroll
    for (int i = 0; i < 4; ++i) {
        int cbase = co0 + wm * 64 + i * 16 + quad * 4;
        #pragma unroll
        for (int r = 0; r < 4; ++r) {
            int c = cbase + r;
            float bv = bz[c];
            float s = 0.f, s2 = 0.f;
            #pragma unroll
            for (int jj = 0; jj < 4; ++jj) {
                int n = n0 + wn * 64 + jj * 16 + l15;
                float v = acc[i][jj][r] + bv;
                if constexpr (U16)
                    wyb[((size_t)b * CH + c) * NSP + n] = (bf16)v;
                else
                    wy[((size_t)b * CH + c) * NSP + n] = v;
                s += v; s2 += v * v;
            }
            s  += __shfl_xor(s, 1);  s2 += __shfl_xor(s2, 1);
            s  += __shfl_xor(s, 2);  s2 += __shfl_xor(s2, 2);
            s  += __shfl_xor(s, 4);  s2 += __shfl_xor(s2, 4);
            s  += __shfl_xor(s, 8);  s2 += __shfl_xor(s2, 8);
            if (l15 == 0) {
                int cl = wm * 64 + i * 16 + quad * 4 + r;
                redS[cl][wn]  = s;
                redS2[cl][wn] = s2;
            }
        }
    }
    __syncthreads();
    if (t < 128) {
        atomicAdd(&sums[co0 + t],      redS[t][0] + redS[t][1]);
        atomicAdd(&sums[CH + co0 + t], redS2[t][0] + redS2[t][1]);
    }
}

// ---------------------------------------------------------------------------
// K4: BN normalize + affine + residual.
//   f32 variant: in-place on d_out (4 elems/thread).
//   b16 variant: reads bf16 wyb (8 elems/thread), writes d_out f32.
// ---------------------------------------------------------------------------
__global__ void bn_finalize(float* __restrict__ out, const float* __restrict__ x,
                            const float* __restrict__ sums,
                            const float* __restrict__ gamma, const float* __restrict__ beta) {
    size_t idx4 = (size_t)blockIdx.x * 256 + threadIdx.x;
    size_t flat = idx4 * 4;
    int ch = (int)((flat >> 10) & 511);
    float S = sums[ch], S2 = sums[CH + ch];
    const float invcnt = 1.0f / (BATCH * NSP);
    float mean = S * invcnt;
    float var = S2 * invcnt - mean * mean;
    float sc = rsqrtf(var + EPSV) * gamma[ch];
    float bi = beta[ch] - mean * sc;
    float4 wv = *(float4*)(out + flat);
    float4 xv = *(const float4*)(x + flat);
    wv.x = wv.x * sc + bi + xv.x;
    wv.y = wv.y * sc + bi + xv.y;
    wv.z = wv.z * sc + bi + xv.z;
    wv.w = wv.w * sc + bi + xv.w;
    *(float4*)(out + flat) = wv;
}

__global__ void bn_finalize_b16(float* __restrict__ out, const float* __restrict__ x,
                                const bf16* __restrict__ wyb,
                                const float* __restrict__ sums,
                                const float* __restrict__ gamma, const float* __restrict__ beta) {
    size_t idx8 = (size_t)blockIdx.x * 256 + threadIdx.x;
    size_t flat = idx8 * 8;
    int ch = (int)((flat >> 10) & 511);
    float S = sums[ch], S2 = sums[CH + ch];
    const float invcnt = 1.0f / (BATCH * NSP);
    float mean = S * invcnt;
    float var = S2 * invcnt - mean * mean;
    float sc = rsqrtf(var + EPSV) * gamma[ch];
    float bi = beta[ch] - mean * sc;
    bf16x8 wv = *(const bf16x8*)(wyb + flat);
    float4 x0 = *(const float4*)(x + flat);
    float4 x1 = *(const float4*)(x + flat + 4);
    float4 o0, o1;
    o0.x = (float)wv[0] * sc + bi + x0.x;
    o0.y = (float)wv[1] * sc + bi + x0.y;
    o0.z = (float)wv[2] * sc + bi + x0.z;
    o0.w = (float)wv[3] * sc + bi + x0.w;
    o1.x = (float)wv[4] * sc + bi + x1.x;
    o1.y = (float)wv[5] * sc + bi + x1.y;
    o1.z = (float)wv[6] * sc + bi + x1.z;
    o1.w = (float)wv[7] * sc + bi + x1.w;
    *(float4*)(out + flat)     = o0;
    *(float4*)(out + flat + 4) = o1;
}

// ---------------------------------------------------------------------------
extern "C" void kernel_launch(void* const* d_in, const int* in_sizes, int n_in,
                              void* d_out, int out_size, void* d_ws, size_t ws_size,
                              hipStream_t stream) {
    const float* x     = (const float*)d_in[0];
    const float* Wg    = (const float*)d_in[1];
    const float* bg    = (const float*)d_in[2];
    const float* Wt    = (const float*)d_in[3];
    const float* bt    = (const float*)d_in[4];
    const float* Wp    = (const float*)d_in[5];
    const float* bp    = (const float*)d_in[6];
    const float* Wz    = (const float*)d_in[7];
    const float* bz    = (const float*)d_in[8];
    const float* gamma = (const float*)d_in[9];
    const float* beta  = (const float*)d_in[10];
    float* out = (float*)d_out;

    char* ws = (char*)d_ws;
    bf16*  y_t   = (bf16*)(ws);                   // [32][4][1024][64]  16,777,216 B
    bf16*  g_t   = (bf16*)(ws + 16777216);        // blocked V tiles   16,777,216 B
    bf16*  wc    = (bf16*)(ws + 33554432);        // [8][768][64]         786,432 B
    bf16*  wzb   = (bf16*)(ws + 34340864);        // [4][512][64]         262,144 B
    float* sums  = (float*)(ws + 34603008);       // [2][512]               4,096 B
    bf16*  wyb   = (bf16*)(ws + 34607104);        // [32][512][1024] bf16 33,554,432 B (optional)
    bool   u16   = ws_size >= (size_t)34607104 + 33554432;

    char* ob = (char*)d_out;                      // d_out as scratch until out_gemm
    bf16* xb    = (bf16*)(ob);                    // [32][8][1024][64] 33,554,432 B
    bf16* theta = (bf16*)(ob + 33554432);         // [32][1024][256]   16,777,216 B
    bf16* phi_t = (bf16*)(ob + 50331648);         // blocked K tiles   16,777,216 B

    prep_weights<<<dim3(2048), dim3(256), 0, stream>>>(Wg, Wt, Wp, Wz, wc, wzb, sums);
    transpose_x<<<dim3(16, 8, 32), dim3(256), 0, stream>>>(x, xb);
    proj_gemm<<<dim3(6, 8, 32), dim3(256), 0, stream>>>(xb, wc, bt, bp, bg, theta, phi_t, g_t);
    attn_kernel<<<dim3(512), dim3(256), 0, stream>>>(theta, phi_t, g_t, y_t);
    if (u16) {
        out_gemm_t<true><<<dim3(8, 4, 32), dim3(256), 0, stream>>>(y_t, wzb, bz, out, wyb, sums);
        bn_finalize_b16<<<dim3(8192), dim3(256), 0, stream>>>(out, x, wyb, sums, gamma, beta);
    } else {
        out_gemm_t<false><<<dim3(8, 4, 32), dim3(256), 0, stream>>>(y_t, wzb, bz, out, wyb, sums);
        bn_finalize<<<dim3(16384), dim3(256), 0, stream>>>(out, x, sums, gamma, beta);
    }
}